// Round 6
// baseline (75.616 us; speedup 1.0000x reference)
//
#include <hip/hip_runtime.h>
#include <hip/hip_bf16.h>
#include <math.h>

#define Bq 8
#define Nq 1024
#define Dq 256
#define Hq 8
#define HDq 32
#define LOG2E 1.44269504f

typedef __attribute__((ext_vector_type(8)))  short short8v;
typedef __attribute__((ext_vector_type(4)))  float f32x4;
typedef __attribute__((ext_vector_type(16))) float f32x16;

// ---------------------------------------------------------------------------
// Kernel 1 (fused role-split):
//  blocks [0,512):   bf16 MFMA GEMM h = x*W^T + b, epilogue -> h_bT (bf16,
//                    transposed) + s_i2/s_j2 (prescaled by LOG2E)
//  blocks [512,2560): pack adj rows into bitmasks adjw[b][i][0:32)
// ---------------------------------------------------------------------------
__global__ __launch_bounds__(256) void gemm_pack(const float* __restrict__ x,
                                                 const float* __restrict__ W,
                                                 const float* __restrict__ Wb,
                                                 const float* __restrict__ a,
                                                 const int* __restrict__ adj,
                                                 __hip_bfloat16* __restrict__ h_bT,
                                                 float* __restrict__ s_i2,
                                                 float* __restrict__ s_j2,
                                                 unsigned* __restrict__ adjw) {
    __shared__ __hip_bfloat16 xs[64][68];
    __shared__ __hip_bfloat16 wsm[64][68];
    __shared__ __hip_bfloat16 ht[64][72];
    const int t = threadIdx.x;
    const int lane = t & 63, wv = t >> 6;

    if (blockIdx.x >= 512) {
        const size_t row = ((size_t)blockIdx.x - 512) * 4 + wv;   // 0..8191
        const int* ar = adj + row * Nq;
        unsigned* wr = adjw + row * 32;
        #pragma unroll
        for (int it = 0; it < 16; ++it) {
            int v = ar[it * 64 + lane];
            unsigned long long mask = __ballot(v != 0);
            if (lane == 0) {
                wr[it * 2 + 0] = (unsigned)mask;
                wr[it * 2 + 1] = (unsigned)(mask >> 32);
            }
        }
        return;
    }

    const int m0 = (blockIdx.x & 127) * 64;
    const int o0 = (blockIdx.x >> 7) * 64;
    const int lo = lane & 31, hi = lane >> 5;
    const int mw = (wv & 1) * 32, ow = (wv >> 1) * 32;
    const int b = m0 >> 10;
    f32x16 acc = 0.f;

    for (int k0 = 0; k0 < 256; k0 += 64) {
        __syncthreads();
        #pragma unroll
        for (int it = 0; it < 4; ++it) {
            int f4  = t + it * 256;
            int row = f4 >> 4;
            int c4  = (f4 & 15) * 4;
            float4 xv = *(const float4*)(x + (size_t)(m0 + row) * 256 + k0 + c4);
            float4 wv2 = *(const float4*)(W + (size_t)(o0 + row) * 256 + k0 + c4);
            union { ushort4 u; __bf16 e[4]; } xb, wb;
            xb.e[0] = (__bf16)xv.x; xb.e[1] = (__bf16)xv.y;
            xb.e[2] = (__bf16)xv.z; xb.e[3] = (__bf16)xv.w;
            wb.e[0] = (__bf16)wv2.x; wb.e[1] = (__bf16)wv2.y;
            wb.e[2] = (__bf16)wv2.z; wb.e[3] = (__bf16)wv2.w;
            *(ushort4*)(&xs[row][c4])  = xb.u;
            *(ushort4*)(&wsm[row][c4]) = wb.u;
        }
        __syncthreads();
        #pragma unroll
        for (int kk = 0; kk < 4; ++kk) {
            short8v av = *(const short8v*)(&xs[mw + lo][kk * 16 + hi * 8]);
            short8v bv = *(const short8v*)(&wsm[ow + lo][kk * 16 + hi * 8]);
            acc = __builtin_amdgcn_mfma_f32_32x32x16_bf16(av, bv, acc, 0, 0, 0);
        }
    }

    __syncthreads();
    const float bias = Wb[o0 + ow + lo];
    #pragma unroll
    for (int rg = 0; rg < 16; ++rg) {
        int row = (rg & 3) + 8 * (rg >> 2) + 4 * hi;
        float v = acc[rg] + bias;
        ht[ow + lo][mw + row] = (__hip_bfloat16)v;
    }
    __syncthreads();

    #pragma unroll
    for (int it = 0; it < 2; ++it) {
        int s8 = t + it * 256;
        int ol = s8 >> 3;
        int n8 = (s8 & 7) * 8;
        short8v v = *(const short8v*)(&ht[ol][n8]);
        int o = o0 + ol;
        size_t drow = (size_t)((b * Hq + (o >> 5)) * HDq + (o & 31));
        *(short8v*)((unsigned short*)h_bT + drow * Nq + (m0 & 1023) + n8) = v;
    }
    if (t < 128) {
        int hd = t >> 6, nl = t & 63;
        const float* ab = a + b * 64;
        float si = 0.f, sj = 0.f;
        #pragma unroll
        for (int d = 0; d < 32; ++d) {
            float hv = (float)ht[hd * 32 + d][nl];
            si += hv * ab[d];
            sj += hv * ab[32 + d];
        }
        int bh = b * Hq + (o0 >> 5) + hd;
        int n  = (m0 & 1023) + nl;
        s_i2[(size_t)bh * Nq + n] = si * LOG2E;
        s_j2[(size_t)bh * Nq + n] = sj * LOG2E;
    }
}

// ---------------------------------------------------------------------------
// Kernel 2: attention v6 — no LDS in the main loop, 128-thr block = 2 waves
// splitting j 512/512 over the same 16 i-rows (32 waves/CU supply). Register
// ping-pong pipeline (load iter u+1 before evaluating iter u) + compile-time
// immediate offsets off 3 hoisted bases. Ends with a 4KB LDS combine of the
// two j-half partials (one barrier), writing NORMALIZED att.
// ---------------------------------------------------------------------------
__global__ __launch_bounds__(128) void attn_v6(const __hip_bfloat16* __restrict__ h_bT,
                                               const unsigned* __restrict__ adjw,
                                               const float* __restrict__ s_i2,
                                               const float* __restrict__ s_j2,
                                               float* __restrict__ att) {
    __shared__ float accs[2][16][33];
    __shared__ float lrow[2][16];
    // bijective XCD swizzle: 4096 blocks, XCD k gets ids [k*512,(k+1)*512)
    // = bh [k*8,(k+1)*8) -> per-XCD L2 holds 8 bh x 64KB = 512KB
    const int id = ((int)blockIdx.x & 7) * 512 + ((int)blockIdx.x >> 3);
    const int bh = id >> 6;
    const int b  = bh >> 3, hh = bh & 7;
    const int i0 = (id & 63) * 16;
    const int t  = threadIdx.x;
    const int lane = t & 63;
    const int wv = t >> 6;                   // j-half
    const int r16 = lane & 15, jg = lane >> 4;
    const int iG = i0 + r16;
    const unsigned shft = jg * 8;

    const float si = s_i2[(size_t)bh * Nq + iG];
    // hoisted bases (fold wv*512 j-offset and jg lane offset)
    const unsigned short* hb0 = (const unsigned short*)h_bT
        + ((size_t)bh * HDq + r16) * Nq + wv * 512 + jg * 8;
    const unsigned short* hb1 = hb0 + 16 * Nq;
    const float* sjb = s_j2 + (size_t)bh * Nq + wv * 512 + jg * 8;

    // all 16 mask words for this wave's 512 j's
    const unsigned* awb = adjw + ((size_t)b * Nq + iG) * 32 + wv * 16;
    unsigned aw[16];
    #pragma unroll
    for (int q = 0; q < 4; ++q) {
        uint4 w4 = *(const uint4*)(awb + q * 4);
        aw[q * 4 + 0] = w4.x; aw[q * 4 + 1] = w4.y;
        aw[q * 4 + 2] = w4.z; aw[q * 4 + 3] = w4.w;
    }

    f32x4 acc0 = 0.f, acc1 = 0.f;
    float l = 0.f;

    auto LOADS = [&](short8v& F0, short8v& F1, float4& V0, float4& V1, int U) {
        F0 = *(const short8v*)(hb0 + U * 32);
        F1 = *(const short8v*)(hb1 + U * 32);
        V0 = *(const float4*)(sjb + U * 32);
        V1 = *(const float4*)(sjb + U * 32 + 4);
    };
    auto EVAL = [&](short8v F0, short8v F1, float4 V0, float4 V1, unsigned awu) {
        unsigned wbits = awu >> shft;
        float sjv[8] = {V0.x, V0.y, V0.z, V0.w, V1.x, V1.y, V1.z, V1.w};
        union { short8v v; __bf16 e[8]; } pa;
        float ls = 0.f;
        #pragma unroll
        for (int e = 0; e < 8; ++e) {
            float sc = si + sjv[e];
            sc = fmaxf(sc, 0.2f * sc);                 // lrelu (log2-scaled)
            sc = ((wbits >> e) & 1u) ? sc : -30000.f;  // mask -> exp2 = 0
            float p = exp2f(sc);
            ls += p;
            pa.e[e] = (__bf16)p;
        }
        l += ls;
        acc0 = __builtin_amdgcn_mfma_f32_16x16x32_bf16(pa.v, F0, acc0, 0, 0, 0);
        acc1 = __builtin_amdgcn_mfma_f32_16x16x32_bf16(pa.v, F1, acc1, 0, 0, 0);
    };

    short8v f0A, f1A, f0B, f1B;
    float4 v0A, v1A, v0B, v1B;
    LOADS(f0A, f1A, v0A, v1A, 0);
    #pragma unroll
    for (int u = 0; u < 16; u += 2) {
        LOADS(f0B, f1B, v0B, v1B, u + 1);
        EVAL(f0A, f1A, v0A, v1A, aw[u]);
        if (u + 2 < 16) LOADS(f0A, f1A, v0A, v1A, u + 2);
        EVAL(f0B, f1B, v0B, v1B, aw[u + 1]);
    }

    // row-sum of l across the 4 jg-groups -> every lane holds its row's sum
    l += __shfl_xor(l, 16);
    l += __shfl_xor(l, 32);

    // combine the two j-halves via LDS (one barrier), write normalized att
    #pragma unroll
    for (int rg = 0; rg < 4; ++rg) {
        accs[wv][jg * 4 + rg][r16]      = acc0[rg];
        accs[wv][jg * 4 + rg][16 + r16] = acc1[rg];
    }
    if (lane < 16) lrow[wv][lane] = l;
    __syncthreads();

    const int row = t >> 3;          // 0..15
    const int c4  = (t & 7) * 4;     // 0..28
    float rl = 1.f / (lrow[0][row] + lrow[1][row]);
    float4 o;
    o.x = (accs[0][row][c4 + 0] + accs[1][row][c4 + 0]) * rl;
    o.y = (accs[0][row][c4 + 1] + accs[1][row][c4 + 1]) * rl;
    o.z = (accs[0][row][c4 + 2] + accs[1][row][c4 + 2]) * rl;
    o.w = (accs[0][row][c4 + 3] + accs[1][row][c4 + 3]) * rl;
    *(float4*)(att + ((size_t)b * Nq + i0 + row) * Dq + hh * HDq + c4) = o;
}

// ---------------------------------------------------------------------------
// Kernel 3: out = LN(att + x) * gamma + beta (torch unbiased, /(std+eps))
// ---------------------------------------------------------------------------
__global__ __launch_bounds__(256) void ln_k(const float* __restrict__ att,
                                            const float* __restrict__ x,
                                            const float* __restrict__ gamma,
                                            const float* __restrict__ beta,
                                            float* __restrict__ out) {
    const int t = threadIdx.x, lane = t & 63, wv = t >> 6;
    const size_t row  = (size_t)blockIdx.x * 4 + wv;
    const size_t base = row * Dq + lane * 4;
    float4 av = *(const float4*)(att + base);
    float4 xv = *(const float4*)(x + base);
    float o0 = av.x + xv.x, o1 = av.y + xv.y;
    float o2 = av.z + xv.z, o3 = av.w + xv.w;
    float s  = o0 + o1 + o2 + o3;
    float sq = o0 * o0 + o1 * o1 + o2 * o2 + o3 * o3;
    #pragma unroll
    for (int off = 32; off; off >>= 1) {
        s  += __shfl_xor(s, off);
        sq += __shfl_xor(sq, off);
    }
    float mean = s * (1.f / 256.f);
    float var  = (sq - 256.f * mean * mean) * (1.f / 255.f);
    var = fmaxf(var, 0.f);
    float inv = 1.f / (sqrtf(var) + 1e-6f);
    float4 g  = *(const float4*)(gamma + lane * 4);
    float4 bt = *(const float4*)(beta + lane * 4);
    float4 ov;
    ov.x = (o0 - mean) * inv * g.x + bt.x;
    ov.y = (o1 - mean) * inv * g.y + bt.y;
    ov.z = (o2 - mean) * inv * g.z + bt.z;
    ov.w = (o3 - mean) * inv * g.w + bt.w;
    *(float4*)(out + base) = ov;
}

// ---------------------------------------------------------------------------
extern "C" void kernel_launch(void* const* d_in, const int* in_sizes, int n_in,
                              void* d_out, int out_size, void* d_ws, size_t ws_size,
                              hipStream_t stream) {
    const float* x     = (const float*)d_in[0];
    const int*   adj   = (const int*)d_in[1];
    const float* W_w   = (const float*)d_in[2];
    const float* W_b   = (const float*)d_in[3];
    const float* a     = (const float*)d_in[4];
    const float* gamma = (const float*)d_in[5];
    const float* beta  = (const float*)d_in[6];
    float* out = (float*)d_out;

    // ws: h_bT [2M bf16 = 4MB] | att [2M f32] | s_i2 [64K] | s_j2 [64K] |
    //     adjw [256K u32]
    __hip_bfloat16* h_bT = (__hip_bfloat16*)d_ws;
    float* att  = (float*)((char*)d_ws + (size_t)Bq * Hq * Nq * HDq * 2);
    float* s_i2 = att + (size_t)Bq * Nq * Dq;
    float* s_j2 = s_i2 + (size_t)Bq * Hq * Nq;
    unsigned* adjw = (unsigned*)(s_j2 + (size_t)Bq * Hq * Nq);

    gemm_pack<<<2560, 256, 0, stream>>>(x, W_w, W_b, a, adj, h_bT, s_i2, s_j2, adjw);
    attn_v6<<<4096, 128, 0, stream>>>(h_bT, adjw, s_i2, s_j2, att);
    ln_k<<<2048, 256, 0, stream>>>(att, x, gamma, beta, out);
}

// Round 8
// 60.007 us; speedup vs baseline: 1.2601x; 1.2601x over previous
//
#include <hip/hip_runtime.h>
#include <hip/hip_bf16.h>
#include <math.h>

#define Bq 8
#define Nq 1024
#define Dq 256
#define Hq 8
#define HDq 32
#define LOG2E 1.44269504f

typedef __attribute__((ext_vector_type(8)))  short short8v;
typedef __attribute__((ext_vector_type(4)))  float f32x4;
typedef __attribute__((ext_vector_type(16))) float f32x16;

__device__ __forceinline__ void gload_lds16(const void* g, void* l) {
    __builtin_amdgcn_global_load_lds(
        (const __attribute__((address_space(1))) void*)g,
        (__attribute__((address_space(3))) void*)l, 16, 0, 0);
}

// ---------------------------------------------------------------------------
// Kernel 1 (fused role-split):
//  blocks [0,512):   bf16 MFMA GEMM h = x*W^T + b, epilogue -> h_bT (bf16,
//                    transposed) + s_i2/s_j2 (prescaled by LOG2E)
//  blocks [512,2560): pack adj rows into bitmasks adjw[b][i][0:32)
// ---------------------------------------------------------------------------
__global__ __launch_bounds__(256) void gemm_pack(const float* __restrict__ x,
                                                 const float* __restrict__ W,
                                                 const float* __restrict__ Wb,
                                                 const float* __restrict__ a,
                                                 const int* __restrict__ adj,
                                                 __hip_bfloat16* __restrict__ h_bT,
                                                 float* __restrict__ s_i2,
                                                 float* __restrict__ s_j2,
                                                 unsigned* __restrict__ adjw) {
    __shared__ __hip_bfloat16 xs[64][68];
    __shared__ __hip_bfloat16 wsm[64][68];
    __shared__ __hip_bfloat16 ht[64][72];
    const int t = threadIdx.x;
    const int lane = t & 63, wv = t >> 6;

    if (blockIdx.x >= 512) {
        const size_t row = ((size_t)blockIdx.x - 512) * 4 + wv;   // 0..8191
        const int* ar = adj + row * Nq;
        unsigned* wr = adjw + row * 32;
        #pragma unroll
        for (int it = 0; it < 16; ++it) {
            int v = ar[it * 64 + lane];
            unsigned long long mask = __ballot(v != 0);
            if (lane == 0) {
                wr[it * 2 + 0] = (unsigned)mask;
                wr[it * 2 + 1] = (unsigned)(mask >> 32);
            }
        }
        return;
    }

    const int m0 = (blockIdx.x & 127) * 64;
    const int o0 = (blockIdx.x >> 7) * 64;
    const int lo = lane & 31, hi = lane >> 5;
    const int mw = (wv & 1) * 32, ow = (wv >> 1) * 32;
    const int b = m0 >> 10;
    f32x16 acc = 0.f;

    for (int k0 = 0; k0 < 256; k0 += 64) {
        __syncthreads();
        #pragma unroll
        for (int it = 0; it < 4; ++it) {
            int f4  = t + it * 256;
            int row = f4 >> 4;
            int c4  = (f4 & 15) * 4;
            float4 xv = *(const float4*)(x + (size_t)(m0 + row) * 256 + k0 + c4);
            float4 wv2 = *(const float4*)(W + (size_t)(o0 + row) * 256 + k0 + c4);
            union { ushort4 u; __bf16 e[4]; } xb, wb;
            xb.e[0] = (__bf16)xv.x; xb.e[1] = (__bf16)xv.y;
            xb.e[2] = (__bf16)xv.z; xb.e[3] = (__bf16)xv.w;
            wb.e[0] = (__bf16)wv2.x; wb.e[1] = (__bf16)wv2.y;
            wb.e[2] = (__bf16)wv2.z; wb.e[3] = (__bf16)wv2.w;
            *(ushort4*)(&xs[row][c4])  = xb.u;
            *(ushort4*)(&wsm[row][c4]) = wb.u;
        }
        __syncthreads();
        #pragma unroll
        for (int kk = 0; kk < 4; ++kk) {
            short8v av = *(const short8v*)(&xs[mw + lo][kk * 16 + hi * 8]);
            short8v bv = *(const short8v*)(&wsm[ow + lo][kk * 16 + hi * 8]);
            acc = __builtin_amdgcn_mfma_f32_32x32x16_bf16(av, bv, acc, 0, 0, 0);
        }
    }

    __syncthreads();
    const float bias = Wb[o0 + ow + lo];
    #pragma unroll
    for (int rg = 0; rg < 16; ++rg) {
        int row = (rg & 3) + 8 * (rg >> 2) + 4 * hi;
        float v = acc[rg] + bias;
        ht[ow + lo][mw + row] = (__hip_bfloat16)v;
    }
    __syncthreads();

    #pragma unroll
    for (int it = 0; it < 2; ++it) {
        int s8 = t + it * 256;
        int ol = s8 >> 3;
        int n8 = (s8 & 7) * 8;
        short8v v = *(const short8v*)(&ht[ol][n8]);
        int o = o0 + ol;
        size_t drow = (size_t)((b * Hq + (o >> 5)) * HDq + (o & 31));
        *(short8v*)((unsigned short*)h_bT + drow * Nq + (m0 & 1023) + n8) = v;
    }
    if (t < 128) {
        int hd = t >> 6, nl = t & 63;
        const float* ab = a + b * 64;
        float si = 0.f, sj = 0.f;
        #pragma unroll
        for (int d = 0; d < 32; ++d) {
            float hv = (float)ht[hd * 32 + d][nl];
            si += hv * ab[d];
            sj += hv * ab[32 + d];
        }
        int bh = b * Hq + (o0 >> 5) + hd;
        int n  = (m0 & 1023) + nl;
        s_i2[(size_t)bh * Nq + n] = si * LOG2E;
        s_j2[(size_t)bh * Nq + n] = sj * LOG2E;
    }
}

// ---------------------------------------------------------------------------
// Kernel 2: attention v7 — LDS-staged via global_load_lds(16B), zero in-loop
// VMEM, XOR-swizzled B-fragment reads (conflict-free), 16x16x32 MFMA PV.
// Block = 4 waves x 16 i-rows = 64 rows of one bh; 1024 blocks; 2 j-chunks
// of 512. hsT rows are LINEAR (global_load_lds requirement); the source
// octet is pre-swizzled (lane ^ (row&7)) and reads XOR the same key.
// Mask indexing: window w covers j in [w*32,(w+1)*32) -> word aw16[w],
// bit jg*8+e  (round-7 bug: treated words as 16-bit halves).
// ---------------------------------------------------------------------------
__global__ __launch_bounds__(256, 4) void attn_v7(const __hip_bfloat16* __restrict__ h_bT,
                                                  const unsigned* __restrict__ adjw,
                                                  const float* __restrict__ s_i2,
                                                  const float* __restrict__ s_j2,
                                                  float* __restrict__ att) {
    __shared__ __hip_bfloat16 hsT[32][512];   // 32KB, linear rows (16B aligned)
    __shared__ float sjs[512];                // 2KB
    const int t = threadIdx.x, lane = t & 63, wv = t >> 6;
    const int id = blockIdx.x;
    const int bh = id >> 4;                   // 16 blocks per bh
    const int b  = bh >> 3, hh = bh & 7;
    const int i0 = (id & 15) * 64 + wv * 16;
    const int r16 = lane & 15, jg = lane >> 4;
    const int iG = i0 + r16;
    const int key = r16 & 7;                  // read-side XOR (octet units)
    const unsigned shbase = jg * 8;

    const float si = s_i2[(size_t)bh * Nq + iG];
    const unsigned short* hb = (const unsigned short*)h_bT + (size_t)bh * HDq * Nq;
    const float* sjb = s_j2 + (size_t)bh * Nq;
    const unsigned* awp = adjw + ((size_t)b * Nq + iG) * 32;
    const __hip_bfloat16* pr0 = &hsT[r16][0];
    const __hip_bfloat16* pr1 = &hsT[r16 + 16][0];

    f32x4 acc0 = 0.f, acc1 = 0.f;
    float l = 0.f;

    for (int ch = 0; ch < 2; ++ch) {
        __syncthreads();                      // previous chunk fully consumed
        // ---- stage: wave wv loads h rows wv*8..+7 (1KB each, linear dest,
        //      source octet pre-swizzled by row key) ----
        #pragma unroll
        for (int it = 0; it < 8; ++it) {
            int r = wv * 8 + it;
            const unsigned short* src = hb + (size_t)r * Nq + ch * 512
                                      + ((lane ^ (r & 7)) << 3);
            gload_lds16(src, &hsT[r][0]);
        }
        if (wv < 2) {
            const float* s4 = sjb + ch * 512 + wv * 256 + lane * 4;
            gload_lds16(s4, &sjs[wv * 256]);
        }
        __syncthreads();                      // drains vmcnt(0) then barrier

        // ---- masks for this chunk: 16 words -> registers (static-indexed) ----
        uint4 q0 = *(const uint4*)(awp + ch * 16);
        uint4 q1 = *(const uint4*)(awp + ch * 16 + 4);
        uint4 q2 = *(const uint4*)(awp + ch * 16 + 8);
        uint4 q3 = *(const uint4*)(awp + ch * 16 + 12);
        unsigned aw16[16] = {q0.x, q0.y, q0.z, q0.w, q1.x, q1.y, q1.z, q1.w,
                             q2.x, q2.y, q2.z, q2.w, q3.x, q3.y, q3.z, q3.w};

        // ---- 16 windows x 32 j ----
        #pragma unroll
        for (int w = 0; w < 16; ++w) {
            unsigned wbits = aw16[w] >> shbase;          // word w, bits jg*8+e
            int po = ((w * 4 + jg) ^ key) << 3;          // swizzled octet -> elems
            short8v fb0 = *(const short8v*)(pr0 + po);
            short8v fb1 = *(const short8v*)(pr1 + po);
            float4 sv0 = *(const float4*)(&sjs[w * 32 + jg * 8]);
            float4 sv1 = *(const float4*)(&sjs[w * 32 + jg * 8 + 4]);
            float sjv[8] = {sv0.x, sv0.y, sv0.z, sv0.w, sv1.x, sv1.y, sv1.z, sv1.w};
            union { short8v v; __bf16 e[8]; } pa;
            float ls = 0.f;
            #pragma unroll
            for (int e = 0; e < 8; ++e) {
                float sc = si + sjv[e];
                sc = fmaxf(sc, 0.2f * sc);                 // lrelu (log2-scaled)
                sc = ((wbits >> e) & 1u) ? sc : -30000.f;  // mask -> exp2 = 0
                float p = exp2f(sc);
                ls += p;
                pa.e[e] = (__bf16)p;
            }
            l += ls;
            acc0 = __builtin_amdgcn_mfma_f32_16x16x32_bf16(pa.v, fb0, acc0, 0, 0, 0);
            acc1 = __builtin_amdgcn_mfma_f32_16x16x32_bf16(pa.v, fb1, acc1, 0, 0, 0);
        }
    }

    // ---- epilogue: fold 1/l in, write normalized att ----
    l += __shfl_xor(l, 16);
    l += __shfl_xor(l, 32);
    float rl = 1.f / l;
    #pragma unroll
    for (int rg = 0; rg < 4; ++rg) {
        int row = jg * 4 + rg;                 // C/D: col=lane&15, row=jg*4+rg
        float r2 = __shfl(rl, row);            // lane 'row' holds that row's l
        size_t base = ((size_t)b * Nq + i0 + row) * Dq + hh * HDq;
        att[base + r16]      = acc0[rg] * r2;
        att[base + 16 + r16] = acc1[rg] * r2;
    }
}

// ---------------------------------------------------------------------------
// Kernel 3: out = LN(att + x) * gamma + beta (torch unbiased, /(std+eps))
// ---------------------------------------------------------------------------
__global__ __launch_bounds__(256) void ln_k(const float* __restrict__ att,
                                            const float* __restrict__ x,
                                            const float* __restrict__ gamma,
                                            const float* __restrict__ beta,
                                            float* __restrict__ out) {
    const int t = threadIdx.x, lane = t & 63, wv = t >> 6;
    const size_t row  = (size_t)blockIdx.x * 4 + wv;
    const size_t base = row * Dq + lane * 4;
    float4 av = *(const float4*)(att + base);
    float4 xv = *(const float4*)(x + base);
    float o0 = av.x + xv.x, o1 = av.y + xv.y;
    float o2 = av.z + xv.z, o3 = av.w + xv.w;
    float s  = o0 + o1 + o2 + o3;
    float sq = o0 * o0 + o1 * o1 + o2 * o2 + o3 * o3;
    #pragma unroll
    for (int off = 32; off; off >>= 1) {
        s  += __shfl_xor(s, off);
        sq += __shfl_xor(sq, off);
    }
    float mean = s * (1.f / 256.f);
    float var  = (sq - 256.f * mean * mean) * (1.f / 255.f);
    var = fmaxf(var, 0.f);
    float inv = 1.f / (sqrtf(var) + 1e-6f);
    float4 g  = *(const float4*)(gamma + lane * 4);
    float4 bt = *(const float4*)(beta + lane * 4);
    float4 ov;
    ov.x = (o0 - mean) * inv * g.x + bt.x;
    ov.y = (o1 - mean) * inv * g.y + bt.y;
    ov.z = (o2 - mean) * inv * g.z + bt.z;
    ov.w = (o3 - mean) * inv * g.w + bt.w;
    *(float4*)(out + base) = ov;
}

// ---------------------------------------------------------------------------
extern "C" void kernel_launch(void* const* d_in, const int* in_sizes, int n_in,
                              void* d_out, int out_size, void* d_ws, size_t ws_size,
                              hipStream_t stream) {
    const float* x     = (const float*)d_in[0];
    const int*   adj   = (const int*)d_in[1];
    const float* W_w   = (const float*)d_in[2];
    const float* W_b   = (const float*)d_in[3];
    const float* a     = (const float*)d_in[4];
    const float* gamma = (const float*)d_in[5];
    const float* beta  = (const float*)d_in[6];
    float* out = (float*)d_out;

    // ws: h_bT [2M bf16 = 4MB] | att [2M f32] | s_i2 [64K] | s_j2 [64K] |
    //     adjw [256K u32]
    __hip_bfloat16* h_bT = (__hip_bfloat16*)d_ws;
    float* att  = (float*)((char*)d_ws + (size_t)Bq * Hq * Nq * HDq * 2);
    float* s_i2 = att + (size_t)Bq * Nq * Dq;
    float* s_j2 = s_i2 + (size_t)Bq * Hq * Nq;
    unsigned* adjw = (unsigned*)(s_j2 + (size_t)Bq * Hq * Nq);

    gemm_pack<<<2560, 256, 0, stream>>>(x, W_w, W_b, a, adj, h_bT, s_i2, s_j2, adjw);
    attn_v7<<<1024, 256, 0, stream>>>(h_bT, adjw, s_i2, s_j2, att);
    ln_k<<<2048, 256, 0, stream>>>(att, x, gamma, beta, out);
}

// Round 9
// 45.966 us; speedup vs baseline: 1.6450x; 1.3055x over previous
//
#include <hip/hip_runtime.h>
#include <hip/hip_bf16.h>
#include <math.h>

#define Bq 8
#define Nq 1024
#define Dq 256
#define Hq 8
#define HDq 32
#define LOG2E 1.44269504f

typedef __attribute__((ext_vector_type(8)))  short short8v;
typedef __attribute__((ext_vector_type(4)))  float f32x4;
typedef __attribute__((ext_vector_type(16))) float f32x16;

__device__ __forceinline__ void gload_lds16(const void* g, void* l) {
    __builtin_amdgcn_global_load_lds(
        (const __attribute__((address_space(1))) void*)g,
        (__attribute__((address_space(3))) void*)l, 16, 0, 0);
}

// ---------------------------------------------------------------------------
// Kernel 1 (fused role-split):
//  blocks [0,512):   bf16 MFMA GEMM h = x*W^T + b, epilogue -> h_bT (bf16,
//                    transposed) + s_i2/s_j2 (prescaled by LOG2E)
//  blocks [512,2560): pack adj rows into bitmasks adjw[b][i][0:32)
// ---------------------------------------------------------------------------
__global__ __launch_bounds__(256) void gemm_pack(const float* __restrict__ x,
                                                 const float* __restrict__ W,
                                                 const float* __restrict__ Wb,
                                                 const float* __restrict__ a,
                                                 const int* __restrict__ adj,
                                                 __hip_bfloat16* __restrict__ h_bT,
                                                 float* __restrict__ s_i2,
                                                 float* __restrict__ s_j2,
                                                 unsigned* __restrict__ adjw) {
    __shared__ __hip_bfloat16 xs[64][68];
    __shared__ __hip_bfloat16 wsm[64][68];
    __shared__ __hip_bfloat16 ht[64][72];
    const int t = threadIdx.x;
    const int lane = t & 63, wv = t >> 6;

    if (blockIdx.x >= 512) {
        const size_t row = ((size_t)blockIdx.x - 512) * 4 + wv;   // 0..8191
        const int* ar = adj + row * Nq;
        unsigned* wr = adjw + row * 32;
        #pragma unroll
        for (int it = 0; it < 16; ++it) {
            int v = ar[it * 64 + lane];
            unsigned long long mask = __ballot(v != 0);
            if (lane == 0) {
                wr[it * 2 + 0] = (unsigned)mask;
                wr[it * 2 + 1] = (unsigned)(mask >> 32);
            }
        }
        return;
    }

    const int m0 = (blockIdx.x & 127) * 64;
    const int o0 = (blockIdx.x >> 7) * 64;
    const int lo = lane & 31, hi = lane >> 5;
    const int mw = (wv & 1) * 32, ow = (wv >> 1) * 32;
    const int b = m0 >> 10;
    f32x16 acc = 0.f;

    for (int k0 = 0; k0 < 256; k0 += 64) {
        __syncthreads();
        #pragma unroll
        for (int it = 0; it < 4; ++it) {
            int f4  = t + it * 256;
            int row = f4 >> 4;
            int c4  = (f4 & 15) * 4;
            float4 xv = *(const float4*)(x + (size_t)(m0 + row) * 256 + k0 + c4);
            float4 wv2 = *(const float4*)(W + (size_t)(o0 + row) * 256 + k0 + c4);
            union { ushort4 u; __bf16 e[4]; } xb, wb;
            xb.e[0] = (__bf16)xv.x; xb.e[1] = (__bf16)xv.y;
            xb.e[2] = (__bf16)xv.z; xb.e[3] = (__bf16)xv.w;
            wb.e[0] = (__bf16)wv2.x; wb.e[1] = (__bf16)wv2.y;
            wb.e[2] = (__bf16)wv2.z; wb.e[3] = (__bf16)wv2.w;
            *(ushort4*)(&xs[row][c4])  = xb.u;
            *(ushort4*)(&wsm[row][c4]) = wb.u;
        }
        __syncthreads();
        #pragma unroll
        for (int kk = 0; kk < 4; ++kk) {
            short8v av = *(const short8v*)(&xs[mw + lo][kk * 16 + hi * 8]);
            short8v bv = *(const short8v*)(&wsm[ow + lo][kk * 16 + hi * 8]);
            acc = __builtin_amdgcn_mfma_f32_32x32x16_bf16(av, bv, acc, 0, 0, 0);
        }
    }

    __syncthreads();
    const float bias = Wb[o0 + ow + lo];
    #pragma unroll
    for (int rg = 0; rg < 16; ++rg) {
        int row = (rg & 3) + 8 * (rg >> 2) + 4 * hi;
        float v = acc[rg] + bias;
        ht[ow + lo][mw + row] = (__hip_bfloat16)v;
    }
    __syncthreads();

    #pragma unroll
    for (int it = 0; it < 2; ++it) {
        int s8 = t + it * 256;
        int ol = s8 >> 3;
        int n8 = (s8 & 7) * 8;
        short8v v = *(const short8v*)(&ht[ol][n8]);
        int o = o0 + ol;
        size_t drow = (size_t)((b * Hq + (o >> 5)) * HDq + (o & 31));
        *(short8v*)((unsigned short*)h_bT + drow * Nq + (m0 & 1023) + n8) = v;
    }
    // s projections: 256 threads, each one 32-dot.
    // t = which*128 + hd*64 + nl  (which: 0=s_i, 1=s_j)
    {
        int which = t >> 7;
        int hd = (t >> 6) & 1, nl = t & 63;
        const float* ab = a + b * 64 + which * 32;
        float s = 0.f;
        #pragma unroll
        for (int d = 0; d < 32; ++d)
            s += (float)ht[hd * 32 + d][nl] * ab[d];
        int bh = b * Hq + (o0 >> 5) + hd;
        int n  = (m0 & 1023) + nl;
        (which ? s_j2 : s_i2)[(size_t)bh * Nq + n] = s * LOG2E;
    }
}

// ---------------------------------------------------------------------------
// Kernel 2: attention v8 — v7 memory structure (global_load_lds staging,
// XOR-swizzled conflict-free B-frag reads, zero in-loop VMEM) with a slimmed
// eval: native v_exp_f32 (__builtin_amdgcn_exp2f), row-sum l computed by a
// third MFMA against an all-ones B (no scalar adds, no epilogue shuffles:
// acc_l[rg] lives in the same lane/reg slot as acc0/acc1[rg]'s row), f32x4
// static-indexed s_j. XCD-bijective block swizzle (128 blocks per XCD,
// 8 whole bh per XCD -> h_bT L2-resident once).
// ---------------------------------------------------------------------------
__global__ __launch_bounds__(256, 4) void attn_v8(const __hip_bfloat16* __restrict__ h_bT,
                                                  const unsigned* __restrict__ adjw,
                                                  const float* __restrict__ s_i2,
                                                  const float* __restrict__ s_j2,
                                                  float* __restrict__ att) {
    __shared__ __hip_bfloat16 hsT[32][512];   // 32KB, linear rows
    __shared__ float sjs[512];                // 2KB
    const int t = threadIdx.x, lane = t & 63, wv = t >> 6;
    // bijective XCD swizzle: 1024 blocks = 8 XCDs x 128
    const int id = ((int)blockIdx.x & 7) * 128 + ((int)blockIdx.x >> 3);
    const int bh = id >> 4;                   // 16 blocks per bh
    const int b  = bh >> 3, hh = bh & 7;
    const int i0 = (id & 15) * 64 + wv * 16;
    const int r16 = lane & 15, jg = lane >> 4;
    const int iG = i0 + r16;
    const int key = r16 & 7;                  // read-side XOR (octet units)
    const unsigned shbase = jg * 8;

    const float si = s_i2[(size_t)bh * Nq + iG];
    const unsigned short* hb = (const unsigned short*)h_bT + (size_t)bh * HDq * Nq;
    const float* sjb = s_j2 + (size_t)bh * Nq;
    const unsigned* awp = adjw + ((size_t)b * Nq + iG) * 32;
    const __hip_bfloat16* pr0 = &hsT[r16][0];
    const __hip_bfloat16* pr1 = &hsT[r16 + 16][0];

    // all-ones bf16 B-fragment (D[r][c] = rowsum(A) for every c)
    short8v ones;
    #pragma unroll
    for (int k = 0; k < 8; ++k) ones[k] = (short)0x3F80;

    f32x4 acc0 = 0.f, acc1 = 0.f, accl = 0.f;

    for (int ch = 0; ch < 2; ++ch) {
        __syncthreads();                      // previous chunk fully consumed
        // stage: wave wv loads h rows wv*8..+7 (source octet pre-swizzled)
        #pragma unroll
        for (int it = 0; it < 8; ++it) {
            int r = wv * 8 + it;
            const unsigned short* src = hb + (size_t)r * Nq + ch * 512
                                      + ((lane ^ (r & 7)) << 3);
            gload_lds16(src, &hsT[r][0]);
        }
        if (wv < 2) {
            const float* s4 = sjb + ch * 512 + wv * 256 + lane * 4;
            gload_lds16(s4, &sjs[wv * 256]);
        }
        __syncthreads();                      // drains vmcnt(0) then barrier

        // masks for this chunk: 16 words -> registers (static-indexed)
        uint4 q0 = *(const uint4*)(awp + ch * 16);
        uint4 q1 = *(const uint4*)(awp + ch * 16 + 4);
        uint4 q2 = *(const uint4*)(awp + ch * 16 + 8);
        uint4 q3 = *(const uint4*)(awp + ch * 16 + 12);
        unsigned aw16[16] = {q0.x, q0.y, q0.z, q0.w, q1.x, q1.y, q1.z, q1.w,
                             q2.x, q2.y, q2.z, q2.w, q3.x, q3.y, q3.z, q3.w};

        // 16 windows x 32 j
        #pragma unroll
        for (int w = 0; w < 16; ++w) {
            unsigned wbits = aw16[w] >> shbase;          // word w, bits jg*8+e
            int po = ((w * 4 + jg) ^ key) << 3;          // swizzled octet
            short8v fb0 = *(const short8v*)(pr0 + po);
            short8v fb1 = *(const short8v*)(pr1 + po);
            f32x4 sv0 = *(const f32x4*)(&sjs[w * 32 + jg * 8]);
            f32x4 sv1 = *(const f32x4*)(&sjs[w * 32 + jg * 8 + 4]);
            union { short8v v; __bf16 e[8]; } pa;
            #pragma unroll
            for (int e = 0; e < 8; ++e) {
                float sc = si + (e < 4 ? sv0[e] : sv1[e - 4]);
                sc = fmaxf(sc, 0.2f * sc);                 // lrelu (log2-scaled)
                sc = ((wbits >> e) & 1u) ? sc : -30000.f;  // mask -> exp2 = 0
                pa.e[e] = (__bf16)__builtin_amdgcn_exp2f(sc);
            }
            acc0 = __builtin_amdgcn_mfma_f32_16x16x32_bf16(pa.v, fb0, acc0, 0, 0, 0);
            acc1 = __builtin_amdgcn_mfma_f32_16x16x32_bf16(pa.v, fb1, acc1, 0, 0, 0);
            accl = __builtin_amdgcn_mfma_f32_16x16x32_bf16(pa.v, ones, accl, 0, 0, 0);
        }
    }

    // epilogue: rows of acc0/acc1/accl align (row = jg*4+rg, col = r16;
    // accl's columns are all equal to the row sum) -> no shuffles.
    #pragma unroll
    for (int rg = 0; rg < 4; ++rg) {
        int row = jg * 4 + rg;
        float rl = 1.f / accl[rg];
        size_t base = ((size_t)b * Nq + i0 + row) * Dq + hh * HDq;
        att[base + r16]      = acc0[rg] * rl;
        att[base + 16 + r16] = acc1[rg] * rl;
    }
}

// ---------------------------------------------------------------------------
// Kernel 3: out = LN(att + x) * gamma + beta (torch unbiased, /(std+eps))
// ---------------------------------------------------------------------------
__global__ __launch_bounds__(256) void ln_k(const float* __restrict__ att,
                                            const float* __restrict__ x,
                                            const float* __restrict__ gamma,
                                            const float* __restrict__ beta,
                                            float* __restrict__ out) {
    const int t = threadIdx.x, lane = t & 63, wv = t >> 6;
    const size_t row  = (size_t)blockIdx.x * 4 + wv;
    const size_t base = row * Dq + lane * 4;
    float4 av = *(const float4*)(att + base);
    float4 xv = *(const float4*)(x + base);
    float o0 = av.x + xv.x, o1 = av.y + xv.y;
    float o2 = av.z + xv.z, o3 = av.w + xv.w;
    float s  = o0 + o1 + o2 + o3;
    float sq = o0 * o0 + o1 * o1 + o2 * o2 + o3 * o3;
    #pragma unroll
    for (int off = 32; off; off >>= 1) {
        s  += __shfl_xor(s, off);
        sq += __shfl_xor(sq, off);
    }
    float mean = s * (1.f / 256.f);
    float var  = (sq - 256.f * mean * mean) * (1.f / 255.f);
    var = fmaxf(var, 0.f);
    float inv = 1.f / (sqrtf(var) + 1e-6f);
    float4 g  = *(const float4*)(gamma + lane * 4);
    float4 bt = *(const float4*)(beta + lane * 4);
    float4 ov;
    ov.x = (o0 - mean) * inv * g.x + bt.x;
    ov.y = (o1 - mean) * inv * g.y + bt.y;
    ov.z = (o2 - mean) * inv * g.z + bt.z;
    ov.w = (o3 - mean) * inv * g.w + bt.w;
    *(float4*)(out + base) = ov;
}

// ---------------------------------------------------------------------------
extern "C" void kernel_launch(void* const* d_in, const int* in_sizes, int n_in,
                              void* d_out, int out_size, void* d_ws, size_t ws_size,
                              hipStream_t stream) {
    const float* x     = (const float*)d_in[0];
    const int*   adj   = (const int*)d_in[1];
    const float* W_w   = (const float*)d_in[2];
    const float* W_b   = (const float*)d_in[3];
    const float* a     = (const float*)d_in[4];
    const float* gamma = (const float*)d_in[5];
    const float* beta  = (const float*)d_in[6];
    float* out = (float*)d_out;

    // ws: h_bT [2M bf16 = 4MB] | att [2M f32] | s_i2 [64K] | s_j2 [64K] |
    //     adjw [256K u32]
    __hip_bfloat16* h_bT = (__hip_bfloat16*)d_ws;
    float* att  = (float*)((char*)d_ws + (size_t)Bq * Hq * Nq * HDq * 2);
    float* s_i2 = att + (size_t)Bq * Nq * Dq;
    float* s_j2 = s_i2 + (size_t)Bq * Hq * Nq;
    unsigned* adjw = (unsigned*)(s_j2 + (size_t)Bq * Hq * Nq);

    gemm_pack<<<2560, 256, 0, stream>>>(x, W_w, W_b, a, adj, h_bT, s_i2, s_j2, adjw);
    attn_v8<<<1024, 256, 0, stream>>>(h_bT, adjw, s_i2, s_j2, att);
    ln_k<<<2048, 256, 0, stream>>>(att, x, gamma, beta, out);
}

// Round 10
// 45.076 us; speedup vs baseline: 1.6775x; 1.0197x over previous
//
#include <hip/hip_runtime.h>
#include <hip/hip_bf16.h>
#include <math.h>

#define Bq 8
#define Nq 1024
#define Dq 256
#define Hq 8
#define HDq 32
#define LOG2E 1.44269504f

typedef __attribute__((ext_vector_type(8)))  short short8v;
typedef __attribute__((ext_vector_type(4)))  float f32x4;
typedef __attribute__((ext_vector_type(16))) float f32x16;

__device__ __forceinline__ void gload_lds16(const void* g, void* l) {
    __builtin_amdgcn_global_load_lds(
        (const __attribute__((address_space(1))) void*)g,
        (__attribute__((address_space(3))) void*)l, 16, 0, 0);
}

// ---------------------------------------------------------------------------
// Kernel 1 (fused role-split):
//  blocks [0,512):   bf16 MFMA GEMM h = x*W^T + b, epilogue -> h_bT (bf16,
//                    transposed) + s_i2/s_j2 (prescaled by LOG2E)
//  blocks [512,2560): pack adj rows into bitmasks adjw[b][i][0:32)
// ---------------------------------------------------------------------------
__global__ __launch_bounds__(256) void gemm_pack(const float* __restrict__ x,
                                                 const float* __restrict__ W,
                                                 const float* __restrict__ Wb,
                                                 const float* __restrict__ a,
                                                 const int* __restrict__ adj,
                                                 __hip_bfloat16* __restrict__ h_bT,
                                                 float* __restrict__ s_i2,
                                                 float* __restrict__ s_j2,
                                                 unsigned* __restrict__ adjw) {
    __shared__ __hip_bfloat16 xs[64][68];
    __shared__ __hip_bfloat16 wsm[64][68];
    __shared__ __hip_bfloat16 ht[64][72];
    const int t = threadIdx.x;
    const int lane = t & 63, wv = t >> 6;

    if (blockIdx.x >= 512) {
        const size_t row = ((size_t)blockIdx.x - 512) * 4 + wv;   // 0..8191
        const int* ar = adj + row * Nq;
        unsigned* wr = adjw + row * 32;
        #pragma unroll
        for (int it = 0; it < 16; ++it) {
            int v = ar[it * 64 + lane];
            unsigned long long mask = __ballot(v != 0);
            if (lane == 0) {
                wr[it * 2 + 0] = (unsigned)mask;
                wr[it * 2 + 1] = (unsigned)(mask >> 32);
            }
        }
        return;
    }

    const int m0 = (blockIdx.x & 127) * 64;
    const int o0 = (blockIdx.x >> 7) * 64;
    const int lo = lane & 31, hi = lane >> 5;
    const int mw = (wv & 1) * 32, ow = (wv >> 1) * 32;
    const int b = m0 >> 10;
    f32x16 acc = 0.f;

    for (int k0 = 0; k0 < 256; k0 += 64) {
        __syncthreads();
        #pragma unroll
        for (int it = 0; it < 4; ++it) {
            int f4  = t + it * 256;
            int row = f4 >> 4;
            int c4  = (f4 & 15) * 4;
            float4 xv = *(const float4*)(x + (size_t)(m0 + row) * 256 + k0 + c4);
            float4 wv2 = *(const float4*)(W + (size_t)(o0 + row) * 256 + k0 + c4);
            union { ushort4 u; __bf16 e[4]; } xb, wb;
            xb.e[0] = (__bf16)xv.x; xb.e[1] = (__bf16)xv.y;
            xb.e[2] = (__bf16)xv.z; xb.e[3] = (__bf16)xv.w;
            wb.e[0] = (__bf16)wv2.x; wb.e[1] = (__bf16)wv2.y;
            wb.e[2] = (__bf16)wv2.z; wb.e[3] = (__bf16)wv2.w;
            *(ushort4*)(&xs[row][c4])  = xb.u;
            *(ushort4*)(&wsm[row][c4]) = wb.u;
        }
        __syncthreads();
        #pragma unroll
        for (int kk = 0; kk < 4; ++kk) {
            short8v av = *(const short8v*)(&xs[mw + lo][kk * 16 + hi * 8]);
            short8v bv = *(const short8v*)(&wsm[ow + lo][kk * 16 + hi * 8]);
            acc = __builtin_amdgcn_mfma_f32_32x32x16_bf16(av, bv, acc, 0, 0, 0);
        }
    }

    __syncthreads();
    const float bias = Wb[o0 + ow + lo];
    #pragma unroll
    for (int rg = 0; rg < 16; ++rg) {
        int row = (rg & 3) + 8 * (rg >> 2) + 4 * hi;
        float v = acc[rg] + bias;
        ht[ow + lo][mw + row] = (__hip_bfloat16)v;
    }
    __syncthreads();

    #pragma unroll
    for (int it = 0; it < 2; ++it) {
        int s8 = t + it * 256;
        int ol = s8 >> 3;
        int n8 = (s8 & 7) * 8;
        short8v v = *(const short8v*)(&ht[ol][n8]);
        int o = o0 + ol;
        size_t drow = (size_t)((b * Hq + (o >> 5)) * HDq + (o & 31));
        *(short8v*)((unsigned short*)h_bT + drow * Nq + (m0 & 1023) + n8) = v;
    }
    // s projections: 256 threads, each one 32-dot.
    {
        int which = t >> 7;
        int hd = (t >> 6) & 1, nl = t & 63;
        const float* ab = a + b * 64 + which * 32;
        float s = 0.f;
        #pragma unroll
        for (int d = 0; d < 32; ++d)
            s += (float)ht[hd * 32 + d][nl] * ab[d];
        int bh = b * Hq + (o0 >> 5) + hd;
        int n  = (m0 & 1023) + nl;
        (which ? s_j2 : s_i2)[(size_t)bh * Nq + n] = s * LOG2E;
    }
}

// ---------------------------------------------------------------------------
// Kernel 2: attention v9 — counted-vmcnt double-buffered staging (T3/T4):
// 4 chunks x 256 j, LDS hsT[2][32][256] (+sjs[2][256]) = 34KB, 4 blocks/CU.
// Per iter: issue chunk c+1's UNIFORM 7 VMEM/wave (4 h-gload_lds covering
// 2 rows each + 1 sjs gload_lds (all waves, redundant same-value) + 2 adjw
// dwordx4 reg loads), then s_waitcnt vmcnt(7) (waits ONLY chunk c's batch;
// the 7 new stay in flight under compute), raw s_barrier, 8 windows of
// ds_read+VALU+MFMA, lgkmcnt(0)+s_barrier. XOR-swizzled (source-preswizzled)
// conflict-free B-frag reads; native v_exp_f32; l via MFMA-vs-ones.
// att output is bf16 (halves attn write + ln read traffic).
// ---------------------------------------------------------------------------
__global__ __launch_bounds__(256, 4) void attn_v9(const __hip_bfloat16* __restrict__ h_bT,
                                                  const unsigned* __restrict__ adjw,
                                                  const float* __restrict__ s_i2,
                                                  const float* __restrict__ s_j2,
                                                  __hip_bfloat16* __restrict__ att) {
    __shared__ __hip_bfloat16 hsT[2][32][256];   // 2 x 16KB, linear rows (512B)
    __shared__ float sjs[2][256];                // 2 x 1KB
    const int t = threadIdx.x, lane = t & 63, wv = t >> 6;
    // bijective XCD swizzle: 1024 blocks = 8 XCDs x 128
    const int id = ((int)blockIdx.x & 7) * 128 + ((int)blockIdx.x >> 3);
    const int bh = id >> 4;                   // 16 blocks per bh
    const int b  = bh >> 3, hh = bh & 7;
    const int i0 = (id & 15) * 64 + wv * 16;
    const int r16 = lane & 15, jg = lane >> 4;
    const int iG = i0 + r16;
    const int key = r16 & 7;                  // read-side XOR (octet units)
    const unsigned shbase = jg * 8;

    const float si = s_i2[(size_t)bh * Nq + iG];
    const unsigned short* hb = (const unsigned short*)h_bT + (size_t)bh * HDq * Nq;
    const float* sjb = s_j2 + (size_t)bh * Nq;
    const unsigned* awp = adjw + ((size_t)b * Nq + iG) * 32;

    // stage chunk ch into buffer nb: 4 h-gloads (2 rows each) + 1 sjs gload
    auto stage = [&](int nb, int ch) {
        #pragma unroll
        for (int it = 0; it < 4; ++it) {
            int rrb = wv * 8 + it * 2;
            int rr  = rrb + (lane >> 5);
            int oct = (lane & 31) ^ (rr & 7);          // source pre-swizzle
            const unsigned short* src = hb + (size_t)rr * Nq + ch * 256 + (oct << 3);
            gload_lds16(src, &hsT[nb][rrb][0]);
        }
        // sjs: every wave loads the full 1KB (same values, race-benign) so
        // the per-wave VMEM count stays uniform (vmcnt bookkeeping).
        gload_lds16(sjb + ch * 256 + lane * 4, &sjs[nb][0]);
    };

    // all-ones bf16 B-fragment (row-sum MFMA)
    short8v ones;
    #pragma unroll
    for (int k = 0; k < 8; ++k) ones[k] = (short)0x3F80;

    f32x4 acc0 = 0.f, acc1 = 0.f, accl = 0.f;
    uint4 qa[2], qb[2];

    // prologue: batch 0 (7 VMEM/wave)
    stage(0, 0);
    qa[0] = *(const uint4*)(awp);
    qb[0] = *(const uint4*)(awp + 4);

    #pragma unroll
    for (int c = 0; c < 4; ++c) {
        const int cb = c & 1;
        if (c < 3) {                           // issue batch c+1 (7 VMEM/wave)
            stage(cb ^ 1, c + 1);
            qa[cb ^ 1] = *(const uint4*)(awp + (c + 1) * 8);
            qb[cb ^ 1] = *(const uint4*)(awp + (c + 1) * 8 + 4);
        }
        if (c < 3) asm volatile("s_waitcnt vmcnt(7)" ::: "memory");
        else       asm volatile("s_waitcnt vmcnt(0)" ::: "memory");
        __builtin_amdgcn_s_barrier();          // chunk c data visible to all
        __builtin_amdgcn_sched_barrier(0);

        unsigned aw8[8] = {qa[cb].x, qa[cb].y, qa[cb].z, qa[cb].w,
                           qb[cb].x, qb[cb].y, qb[cb].z, qb[cb].w};
        const __hip_bfloat16* pr0 = &hsT[cb][r16][0];
        const __hip_bfloat16* pr1 = &hsT[cb][r16 + 16][0];

        #pragma unroll
        for (int w = 0; w < 8; ++w) {
            unsigned wbits = aw8[w] >> shbase;           // word w, bits jg*8+e
            int po = ((w * 4 + jg) ^ key) << 3;          // swizzled octet
            short8v fb0 = *(const short8v*)(pr0 + po);
            short8v fb1 = *(const short8v*)(pr1 + po);
            f32x4 sv0 = *(const f32x4*)(&sjs[cb][w * 32 + jg * 8]);
            f32x4 sv1 = *(const f32x4*)(&sjs[cb][w * 32 + jg * 8 + 4]);
            union { short8v v; __bf16 e[8]; } pa;
            #pragma unroll
            for (int e = 0; e < 8; ++e) {
                float sc = si + (e < 4 ? sv0[e] : sv1[e - 4]);
                sc = fmaxf(sc, 0.2f * sc);                 // lrelu (log2-scaled)
                sc = ((wbits >> e) & 1u) ? sc : -30000.f;  // mask -> exp2 = 0
                pa.e[e] = (__bf16)__builtin_amdgcn_exp2f(sc);
            }
            acc0 = __builtin_amdgcn_mfma_f32_16x16x32_bf16(pa.v, fb0, acc0, 0, 0, 0);
            acc1 = __builtin_amdgcn_mfma_f32_16x16x32_bf16(pa.v, fb1, acc1, 0, 0, 0);
            accl = __builtin_amdgcn_mfma_f32_16x16x32_bf16(pa.v, ones, accl, 0, 0, 0);
        }
        asm volatile("s_waitcnt lgkmcnt(0)" ::: "memory");
        __builtin_amdgcn_s_barrier();          // buf cb free for overwrite
    }

    // epilogue: rows of acc0/acc1/accl align -> no shuffles; bf16 store
    #pragma unroll
    for (int rg = 0; rg < 4; ++rg) {
        int row = jg * 4 + rg;
        float rl = 1.f / accl[rg];
        size_t base = ((size_t)b * Nq + i0 + row) * Dq + hh * HDq;
        att[base + r16]      = (__hip_bfloat16)(acc0[rg] * rl);
        att[base + 16 + r16] = (__hip_bfloat16)(acc1[rg] * rl);
    }
}

// ---------------------------------------------------------------------------
// Kernel 3: out = LN(att(bf16) + x) * gamma + beta (torch unbiased, /(std+eps))
// ---------------------------------------------------------------------------
__global__ __launch_bounds__(256) void ln_k(const __hip_bfloat16* __restrict__ att,
                                            const float* __restrict__ x,
                                            const float* __restrict__ gamma,
                                            const float* __restrict__ beta,
                                            float* __restrict__ out) {
    const int t = threadIdx.x, lane = t & 63, wv = t >> 6;
    const size_t row  = (size_t)blockIdx.x * 4 + wv;
    const size_t base = row * Dq + lane * 4;
    union { ushort4 u; __hip_bfloat16 e[4]; } av;
    av.u = *(const ushort4*)((const unsigned short*)att + base);
    float4 xv = *(const float4*)(x + base);
    float o0 = (float)av.e[0] + xv.x, o1 = (float)av.e[1] + xv.y;
    float o2 = (float)av.e[2] + xv.z, o3 = (float)av.e[3] + xv.w;
    float s  = o0 + o1 + o2 + o3;
    float sq = o0 * o0 + o1 * o1 + o2 * o2 + o3 * o3;
    #pragma unroll
    for (int off = 32; off; off >>= 1) {
        s  += __shfl_xor(s, off);
        sq += __shfl_xor(sq, off);
    }
    float mean = s * (1.f / 256.f);
    float var  = (sq - 256.f * mean * mean) * (1.f / 255.f);
    var = fmaxf(var, 0.f);
    float inv = 1.f / (sqrtf(var) + 1e-6f);
    float4 g  = *(const float4*)(gamma + lane * 4);
    float4 bt = *(const float4*)(beta + lane * 4);
    float4 ov;
    ov.x = (o0 - mean) * inv * g.x + bt.x;
    ov.y = (o1 - mean) * inv * g.y + bt.y;
    ov.z = (o2 - mean) * inv * g.z + bt.z;
    ov.w = (o3 - mean) * inv * g.w + bt.w;
    *(float4*)(out + base) = ov;
}

// ---------------------------------------------------------------------------
extern "C" void kernel_launch(void* const* d_in, const int* in_sizes, int n_in,
                              void* d_out, int out_size, void* d_ws, size_t ws_size,
                              hipStream_t stream) {
    const float* x     = (const float*)d_in[0];
    const int*   adj   = (const int*)d_in[1];
    const float* W_w   = (const float*)d_in[2];
    const float* W_b   = (const float*)d_in[3];
    const float* a     = (const float*)d_in[4];
    const float* gamma = (const float*)d_in[5];
    const float* beta  = (const float*)d_in[6];
    float* out = (float*)d_out;

    // ws: h_bT [2M bf16 = 4MB] | att [2M bf16 = 4MB] | s_i2 [64K] | s_j2 [64K]
    //     | adjw [256K u32]
    __hip_bfloat16* h_bT = (__hip_bfloat16*)d_ws;
    __hip_bfloat16* att  = (__hip_bfloat16*)((char*)d_ws + (size_t)Bq * Hq * Nq * HDq * 2);
    float* s_i2 = (float*)((char*)att + (size_t)Bq * Nq * Dq * 2);
    float* s_j2 = s_i2 + (size_t)Bq * Hq * Nq;
    unsigned* adjw = (unsigned*)(s_j2 + (size_t)Bq * Hq * Nq);

    gemm_pack<<<2560, 256, 0, stream>>>(x, W_w, W_b, a, adj, h_bT, s_i2, s_j2, adjw);
    attn_v9<<<1024, 256, 0, stream>>>(h_bT, adjw, s_i2, s_j2, att);
    ln_k<<<2048, 256, 0, stream>>>(att, x, gamma, beta, out);
}